// Round 1
// baseline (741.850 us; speedup 1.0000x reference)
//
#include <hip/hip_runtime.h>

// MIPTCell: proj = e @ [Wp;Wth;Wr;Wi]^T + b  (M=8192, N=4*2048, K=2048)
// bf16 32x32x16 MFMA GEMM fused with sigmoid/rot/gate epilogue.
//
// 8-phase-style schedule (m201 template adapted):
//   block = 512 thr / 8 waves; tile 256 rows x 64 dcols x 4 mats (eff 256x256)
//   BK=64, double-buffered LDS (128 KB), 4 phases per K-tile:
//     {prefetch gloads (4,2,2,0 spread) || 6 ds_read_b128} -> s_barrier ->
//     setprio(1) 8xMFMA setprio(0) -> [q3: vmcnt(0)] -> s_barrier
//   Raw s_barrier (not __syncthreads) so prefetch loads stay in flight.
//   XOR-8 chunk swizzle: LDS(row, slot s) holds global chunk s ^ (row&7);
//   applied on the global source (gload_lds writes linearly) and on ds_read.
//   Wave (wr=w>>1, wc=w&1) owns rows wr*64+{0,32}, dcols wc*32+L, all 4 mats
//   -> acc[2][4] f32x16, epilogue register-local (same layout as prior kernel).

typedef float f32x16 __attribute__((ext_vector_type(16)));
typedef __bf16 bf16x8 __attribute__((ext_vector_type(8)));
typedef short short8 __attribute__((ext_vector_type(8)));

__device__ __forceinline__ unsigned short f2bf(float f) {
    unsigned u = __float_as_uint(f);
    u += 0x7fffu + ((u >> 16) & 1u);   // round-to-nearest-even
    return (unsigned short)(u >> 16);
}

// Fused fp32->bf16 convert for all 5 tensors in ONE launch.
__global__ __launch_bounds__(256) void cvt_all(
    const float* __restrict__ W_p, const float* __restrict__ W_th,
    const float* __restrict__ W_r, const float* __restrict__ W_i,
    const float* __restrict__ e_t,
    unsigned short* __restrict__ Wbf, unsigned short* __restrict__ Ebf) {
    const long i = (long)blockIdx.x * 256 + threadIdx.x;   // < 4194304
    const float* src;
    unsigned short* dst;
    size_t local;
    if (i < 2097152) {
        const int m = (int)(i >> 19);
        local = (size_t)(i & 524287) * 8;
        src = (m == 0) ? W_p : (m == 1) ? W_th : (m == 2) ? W_r : W_i;
        dst = Wbf + (size_t)m * 4194304 + local;
    } else {
        local = (size_t)(i - 2097152) * 8;
        src = e_t;
        dst = Ebf + local;
    }
    const float4* s4 = (const float4*)(src + local);
    float4 v0 = s4[0], v1 = s4[1];
    ushort4 o0, o1;
    o0.x = f2bf(v0.x); o0.y = f2bf(v0.y); o0.z = f2bf(v0.z); o0.w = f2bf(v0.w);
    o1.x = f2bf(v1.x); o1.y = f2bf(v1.y); o1.z = f2bf(v1.z); o1.w = f2bf(v1.w);
    ((ushort4*)dst)[0] = o0;
    ((ushort4*)dst)[1] = o1;
}

__device__ __forceinline__ void load16_lds(const unsigned short* g, unsigned short* l) {
    __builtin_amdgcn_global_load_lds((const __attribute__((address_space(1))) void*)g,
                                     (__attribute__((address_space(3))) void*)l,
                                     16, 0, 0);
}

__device__ __forceinline__ bf16x8 ldfrag(const unsigned short* p) {
    return __builtin_bit_cast(bf16x8, *(const short8*)p);
}

__global__ __launch_bounds__(512, 2) void mipt_main(
    const unsigned short* __restrict__ E,   // [8192][2048] bf16
    const unsigned short* __restrict__ W,   // [8192][2048] bf16 (Wp;Wth;Wr;Wi)
    const float* __restrict__ b_p, const float* __restrict__ b_th,
    const float* __restrict__ b_r, const float* __restrict__ b_i,
    const float* __restrict__ h_prev,       // [8192][4096] fp32
    float* __restrict__ out)                // [8192][4096] fp32
{
    __shared__ unsigned short As[2 * 256 * 64];   // 64 KB, 2 buffers
    __shared__ unsigned short Bs[2 * 256 * 64];   // 64 KB, 2 buffers

    const int tid  = threadIdx.x;
    const int w    = tid >> 6;     // 0..7
    const int lane = tid & 63;
    const int wr   = w >> 1;       // 0..3 : 64-row group
    const int wc   = w & 1;        // 0..1 : 32-dcol group

    // Bijective XCD swizzle (1024 blocks, 1024 % 8 == 0): each XCD gets 4
    // d-tiles (4 x 1MB B-panels, L2-resident) x all 32 m-tiles.
    const int bid = (int)blockIdx.x;
    const int swz = (bid & 7) * 128 + (bid >> 3);
    const int m0 = (swz & 31) * 256;
    const int n0 = (swz >> 5) * 64;

    f32x16 acc[2][4];
#pragma unroll
    for (int i = 0; i < 2; ++i)
#pragma unroll
        for (int j = 0; j < 4; ++j)
#pragma unroll
            for (int r = 0; r < 16; ++r) acc[i][j][r] = 0.f;

    // ---- staging addressing ----
    // Wave w stages A rows [w*32,w*32+32) and Bs rows [w*32,w*32+32).
    // Per gload: 8 rows (128B each), lane -> row sr=lane>>3, slot lane&7.
    // Pre-swizzled global source: chunk_g = (lane&7) ^ sr  (both-sides XOR-8).
    const int sr = lane >> 3;
    const int sc = ((lane & 7) ^ sr) * 8;
    const unsigned short* Ag = E + (size_t)(m0 + w * 32 + sr) * 2048 + sc;
    // Bs row rb = mat*64 + dd : wave w -> mat = w>>1, dd = (w&1)*32 + j*8 + sr
    const unsigned short* Bg = W + (size_t)(wr * 2048 + n0 + wc * 32 + sr) * 2048 + sc;
    const int dA = w * 2048;   // element offset of wave's 32-row LDS panel

    // ---- fragment addressing (32x32x16: A[m=lane&31][k=(lane>>5)*8+j]) ----
    const int L  = lane & 31;
    const int hi = lane >> 5;
    const int r7 = L & 7;
    const int aoff = (wr * 64 + L) * 64;   // A row = wr*64 + ti*32 + L
    const int boff = (wc * 32 + L) * 64;   // B row = tj*64 + wc*32 + L

    // ---- prologue: stage K-tile 0 into buffer 0 ----
#pragma unroll
    for (int j = 0; j < 4; ++j) {
        load16_lds(Ag + (size_t)(j * 8) * 2048, As + dA + j * 512);
        load16_lds(Bg + (size_t)(j * 8) * 2048, Bs + dA + j * 512);
    }
    asm volatile("s_waitcnt vmcnt(0)" ::: "memory");
    __builtin_amdgcn_s_barrier();

#pragma unroll 1
    for (int t = 0; t < 32; ++t) {
        const int so = (t & 1) << 14;      // current buffer offset (elems)
        const int sn = so ^ 16384;         // next buffer offset
        const bool pf = (t < 31);
        const unsigned short* Agt = Ag + (size_t)(t + 1) * 64;
        const unsigned short* Bgt = Bg + (size_t)(t + 1) * 64;
        const unsigned short* aC = As + so + aoff;
        const unsigned short* bC = Bs + so + boff;
        unsigned short* dAn = As + sn + dA;
        unsigned short* dBn = Bs + sn + dA;

#pragma unroll
        for (int q = 0; q < 4; ++q) {
            // prefetch next K-tile, spread {4,2,2,0} so last issue is >=1
            // full phase before the q3 vmcnt(0)
            if (pf) {
                if (q == 0) {
                    load16_lds(Agt,                 dAn);
                    load16_lds(Bgt,                 dBn);
                    load16_lds(Agt + (size_t)8 * 2048,  dAn + 512);
                    load16_lds(Bgt + (size_t)8 * 2048,  dBn + 512);
                } else if (q == 1) {
                    load16_lds(Agt + (size_t)16 * 2048, dAn + 1024);
                    load16_lds(Bgt + (size_t)16 * 2048, dBn + 1024);
                } else if (q == 2) {
                    load16_lds(Agt + (size_t)24 * 2048, dAn + 1536);
                    load16_lds(Bgt + (size_t)24 * 2048, dBn + 1536);
                }
            }
            // quadrant q covers k = 16q..16q+15 ; chunk = 2q + hi
            const int qo = ((2 * q + hi) ^ r7) * 8;
            bf16x8 a0 = ldfrag(aC + qo);
            bf16x8 a1 = ldfrag(aC + 2048 + qo);
            bf16x8 b0 = ldfrag(bC + qo);
            bf16x8 b1 = ldfrag(bC + 4096 + qo);
            bf16x8 b2 = ldfrag(bC + 8192 + qo);
            bf16x8 b3 = ldfrag(bC + 12288 + qo);
            __builtin_amdgcn_s_barrier();
            __builtin_amdgcn_s_setprio(1);
            acc[0][0] = __builtin_amdgcn_mfma_f32_32x32x16_bf16(a0, b0, acc[0][0], 0, 0, 0);
            acc[1][0] = __builtin_amdgcn_mfma_f32_32x32x16_bf16(a1, b0, acc[1][0], 0, 0, 0);
            acc[0][1] = __builtin_amdgcn_mfma_f32_32x32x16_bf16(a0, b1, acc[0][1], 0, 0, 0);
            acc[1][1] = __builtin_amdgcn_mfma_f32_32x32x16_bf16(a1, b1, acc[1][1], 0, 0, 0);
            acc[0][2] = __builtin_amdgcn_mfma_f32_32x32x16_bf16(a0, b2, acc[0][2], 0, 0, 0);
            acc[1][2] = __builtin_amdgcn_mfma_f32_32x32x16_bf16(a1, b2, acc[1][2], 0, 0, 0);
            acc[0][3] = __builtin_amdgcn_mfma_f32_32x32x16_bf16(a0, b3, acc[0][3], 0, 0, 0);
            acc[1][3] = __builtin_amdgcn_mfma_f32_32x32x16_bf16(a1, b3, acc[1][3], 0, 0, 0);
            __builtin_amdgcn_s_setprio(0);
            if (q == 3 && pf) asm volatile("s_waitcnt vmcnt(0)" ::: "memory");
            __builtin_amdgcn_s_barrier();
        }
    }

    // ---- fused epilogue ----
    // C/D 32x32: col = lane&31, row = 4*(lane>>5) + (reg&3) + 8*(reg>>2)
    // acc[ti][0]=p_lin, [1]=theta, [2]=inp_re, [3]=inp_im
    const int col = n0 + wc * 32 + L;
    const float bp = b_p[col], bt = b_th[col], br = b_r[col], bi = b_i[col];
    const int rowb = m0 + wr * 64 + 4 * hi;
#pragma unroll
    for (int ti = 0; ti < 2; ++ti) {
#pragma unroll
        for (int r = 0; r < 16; ++r) {
            const int row = rowb + ti * 32 + (r & 3) + 8 * (r >> 2);
            const float pl  = acc[ti][0][r] + bp;
            const float th  = acc[ti][1][r] + bt;
            const float ire = acc[ti][2][r] + br;
            const float iim = acc[ti][3][r] + bi;
            const float p = 1.f / (1.f + __expf(-pl));
            float s, ct;
            __sincosf(th, &s, &ct);
            const size_t base = (size_t)row * 4096 + col;
            const float hre = h_prev[base];
            const float him = h_prev[base + 2048];
            const float rre = ct * hre - s * him;
            const float rim = s * hre + ct * him;
            out[base]        = (1.f - p) * rre + p * ire;
            out[base + 2048] = (1.f - p) * rim + p * iim;
        }
    }
}

extern "C" void kernel_launch(void* const* d_in, const int* in_sizes, int n_in,
                              void* d_out, int out_size, void* d_ws, size_t ws_size,
                              hipStream_t stream) {
    (void)in_sizes; (void)n_in; (void)out_size; (void)ws_size;
    const float* e_t   = (const float*)d_in[0];
    const float* h_prv = (const float*)d_in[1];
    const float* W_p   = (const float*)d_in[2];
    const float* b_p   = (const float*)d_in[3];
    const float* W_th  = (const float*)d_in[4];
    const float* b_th  = (const float*)d_in[5];
    const float* W_r   = (const float*)d_in[6];
    const float* b_r   = (const float*)d_in[7];
    const float* W_i   = (const float*)d_in[8];
    const float* b_i   = (const float*)d_in[9];
    float* out = (float*)d_out;

    // workspace: W_cat bf16 [8192][2048] (32MB) then E bf16 [8192][2048] (32MB)
    unsigned short* Wbf = (unsigned short*)d_ws;
    unsigned short* Ebf = Wbf + (size_t)8192 * 2048;

    cvt_all<<<16384, 256, 0, stream>>>(W_p, W_th, W_r, W_i, e_t, Wbf, Ebf);

    // 1024 blocks: 32 m-tiles (256 rows) x 32 d-tiles (64 dcols x 4 mats)
    mipt_main<<<1024, 512, 0, stream>>>(Ebf, Wbf, b_p, b_th, b_r, b_i, h_prv, out);
}

// Round 2
// 652.602 us; speedup vs baseline: 1.1368x; 1.1368x over previous
//
#include <hip/hip_runtime.h>

// MIPTCell: proj = e @ [Wp;Wth;Wr;Wi]^T + b  (M=8192, N=4*2048, K=2048)
// bf16 32x32x16 MFMA GEMM fused with sigmoid/rot/gate epilogue.
//
// Schedule (round 2):
//   block = 512 thr / 8 waves; tile 256 rows x 64 dcols x 4 mats (eff 256x256)
//   BK=64, double-buffered LDS (128 KB), 4 phases per K-tile:
//     q0: issue ALL 8 next-tile gloads  (max distance to the q3 vmcnt(0))
//     each phase: 6 ds_read_b128 -> s_barrier -> setprio(1) 8xMFMA setprio(0)
//                 -> [q3: vmcnt(0)] -> s_barrier
//   Raw s_barrier (not __syncthreads) so prefetch loads stay in flight.
//   Grid: m-tiles fast, n-tiles slow (NO XCD swizzle) — keeps all XCDs on the
//   same narrow n-band so E/W panels are shared through L3 (fetch ~273 MB).
//   XOR-8 chunk swizzle: LDS(row, slot s) holds global chunk s ^ (row&7);
//   applied on the global source (gload_lds writes linearly) and on ds_read.
//   Wave (wr=w>>1, wc=w&1) owns rows wr*64+{0,32}, dcols wc*32+L, all 4 mats
//   -> acc[2][4] f32x16, epilogue register-local.

typedef float f32x16 __attribute__((ext_vector_type(16)));
typedef __bf16 bf16x8 __attribute__((ext_vector_type(8)));
typedef short short8 __attribute__((ext_vector_type(8)));

__device__ __forceinline__ unsigned short f2bf(float f) {
    unsigned u = __float_as_uint(f);
    u += 0x7fffu + ((u >> 16) & 1u);   // round-to-nearest-even
    return (unsigned short)(u >> 16);
}

// Fused fp32->bf16 convert for all 5 tensors in ONE launch.
__global__ __launch_bounds__(256) void cvt_all(
    const float* __restrict__ W_p, const float* __restrict__ W_th,
    const float* __restrict__ W_r, const float* __restrict__ W_i,
    const float* __restrict__ e_t,
    unsigned short* __restrict__ Wbf, unsigned short* __restrict__ Ebf) {
    const long i = (long)blockIdx.x * 256 + threadIdx.x;   // < 4194304
    const float* src;
    unsigned short* dst;
    size_t local;
    if (i < 2097152) {
        const int m = (int)(i >> 19);
        local = (size_t)(i & 524287) * 8;
        src = (m == 0) ? W_p : (m == 1) ? W_th : (m == 2) ? W_r : W_i;
        dst = Wbf + (size_t)m * 4194304 + local;
    } else {
        local = (size_t)(i - 2097152) * 8;
        src = e_t;
        dst = Ebf + local;
    }
    const float4* s4 = (const float4*)(src + local);
    float4 v0 = s4[0], v1 = s4[1];
    ushort4 o0, o1;
    o0.x = f2bf(v0.x); o0.y = f2bf(v0.y); o0.z = f2bf(v0.z); o0.w = f2bf(v0.w);
    o1.x = f2bf(v1.x); o1.y = f2bf(v1.y); o1.z = f2bf(v1.z); o1.w = f2bf(v1.w);
    ((ushort4*)dst)[0] = o0;
    ((ushort4*)dst)[1] = o1;
}

__device__ __forceinline__ void load16_lds(const unsigned short* g, unsigned short* l) {
    __builtin_amdgcn_global_load_lds((const __attribute__((address_space(1))) void*)g,
                                     (__attribute__((address_space(3))) void*)l,
                                     16, 0, 0);
}

__device__ __forceinline__ bf16x8 ldfrag(const unsigned short* p) {
    return __builtin_bit_cast(bf16x8, *(const short8*)p);
}

__global__ __launch_bounds__(512, 2) void mipt_main(
    const unsigned short* __restrict__ E,   // [8192][2048] bf16
    const unsigned short* __restrict__ W,   // [8192][2048] bf16 (Wp;Wth;Wr;Wi)
    const float* __restrict__ b_p, const float* __restrict__ b_th,
    const float* __restrict__ b_r, const float* __restrict__ b_i,
    const float* __restrict__ h_prev,       // [8192][4096] fp32
    float* __restrict__ out)                // [8192][4096] fp32
{
    __shared__ unsigned short As[2 * 256 * 64];   // 64 KB, 2 buffers
    __shared__ unsigned short Bs[2 * 256 * 64];   // 64 KB, 2 buffers

    const int tid  = threadIdx.x;
    const int w    = tid >> 6;     // 0..7
    const int lane = tid & 63;
    const int wr   = w >> 1;       // 0..3 : 64-row group
    const int wc   = w & 1;        // 0..1 : 32-dcol group

    // m-tiles fast (blockIdx.x), n-tiles slow (blockIdx.y): all XCDs stream
    // the same E-panels in sync and share a narrow W band -> L3 absorbs reuse.
    const int m0 = blockIdx.x * 256;
    const int n0 = blockIdx.y * 64;

    f32x16 acc[2][4];
#pragma unroll
    for (int i = 0; i < 2; ++i)
#pragma unroll
        for (int j = 0; j < 4; ++j)
#pragma unroll
            for (int r = 0; r < 16; ++r) acc[i][j][r] = 0.f;

    // ---- staging addressing ----
    // Wave w stages A rows [w*32,w*32+32) and Bs rows [w*32,w*32+32).
    // Per gload: 8 rows (128B each), lane -> row sr=lane>>3, slot lane&7.
    // Pre-swizzled global source: chunk_g = (lane&7) ^ sr  (both-sides XOR-8).
    const int sr = lane >> 3;
    const int sc = ((lane & 7) ^ sr) * 8;
    const unsigned short* Ag = E + (size_t)(m0 + w * 32 + sr) * 2048 + sc;
    // Bs row rb = mat*64 + dd : wave w -> mat = w>>1, dd = (w&1)*32 + j*8 + sr
    const unsigned short* Bg = W + (size_t)(wr * 2048 + n0 + wc * 32 + sr) * 2048 + sc;
    const int dA = w * 2048;   // element offset of wave's 32-row LDS panel

    // ---- fragment addressing (32x32x16: A[m=lane&31][k=(lane>>5)*8+j]) ----
    const int L  = lane & 31;
    const int hi = lane >> 5;
    const int r7 = L & 7;
    const int aoff = (wr * 64 + L) * 64;   // A row = wr*64 + ti*32 + L
    const int boff = (wc * 32 + L) * 64;   // B row = tj*64 + wc*32 + L

    // ---- prologue: stage K-tile 0 into buffer 0 ----
#pragma unroll
    for (int j = 0; j < 4; ++j) {
        load16_lds(Ag + (size_t)(j * 8) * 2048, As + dA + j * 512);
        load16_lds(Bg + (size_t)(j * 8) * 2048, Bs + dA + j * 512);
    }
    asm volatile("s_waitcnt vmcnt(0)" ::: "memory");
    __builtin_amdgcn_s_barrier();

#pragma unroll 1
    for (int t = 0; t < 32; ++t) {
        const int so = (t & 1) << 14;      // current buffer offset (elems)
        const int sn = so ^ 16384;         // next buffer offset
        const bool pf = (t < 31);
        const unsigned short* Agt = Ag + (size_t)(t + 1) * 64;
        const unsigned short* Bgt = Bg + (size_t)(t + 1) * 64;
        const unsigned short* aC = As + so + aoff;
        const unsigned short* bC = Bs + so + boff;
        unsigned short* dAn = As + sn + dA;
        unsigned short* dBn = Bs + sn + dA;

#pragma unroll
        for (int q = 0; q < 4; ++q) {
            // Issue the ENTIRE next K-tile at q0: the q3 vmcnt(0) then
            // enforces only loads issued ~4 phases (>=600 cyc) earlier.
            if (pf && q == 0) {
#pragma unroll
                for (int j = 0; j < 4; ++j) {
                    load16_lds(Agt + (size_t)(j * 8) * 2048, dAn + j * 512);
                    load16_lds(Bgt + (size_t)(j * 8) * 2048, dBn + j * 512);
                }
            }
            // quadrant q covers k = 16q..16q+15 ; chunk = 2q + hi
            const int qo = ((2 * q + hi) ^ r7) * 8;
            bf16x8 a0 = ldfrag(aC + qo);
            bf16x8 a1 = ldfrag(aC + 2048 + qo);
            bf16x8 b0 = ldfrag(bC + qo);
            bf16x8 b1 = ldfrag(bC + 4096 + qo);
            bf16x8 b2 = ldfrag(bC + 8192 + qo);
            bf16x8 b3 = ldfrag(bC + 12288 + qo);
            __builtin_amdgcn_s_barrier();
            __builtin_amdgcn_s_setprio(1);
            acc[0][0] = __builtin_amdgcn_mfma_f32_32x32x16_bf16(a0, b0, acc[0][0], 0, 0, 0);
            acc[1][0] = __builtin_amdgcn_mfma_f32_32x32x16_bf16(a1, b0, acc[1][0], 0, 0, 0);
            acc[0][1] = __builtin_amdgcn_mfma_f32_32x32x16_bf16(a0, b1, acc[0][1], 0, 0, 0);
            acc[1][1] = __builtin_amdgcn_mfma_f32_32x32x16_bf16(a1, b1, acc[1][1], 0, 0, 0);
            acc[0][2] = __builtin_amdgcn_mfma_f32_32x32x16_bf16(a0, b2, acc[0][2], 0, 0, 0);
            acc[1][2] = __builtin_amdgcn_mfma_f32_32x32x16_bf16(a1, b2, acc[1][2], 0, 0, 0);
            acc[0][3] = __builtin_amdgcn_mfma_f32_32x32x16_bf16(a0, b3, acc[0][3], 0, 0, 0);
            acc[1][3] = __builtin_amdgcn_mfma_f32_32x32x16_bf16(a1, b3, acc[1][3], 0, 0, 0);
            __builtin_amdgcn_s_setprio(0);
            if (q == 3 && pf) asm volatile("s_waitcnt vmcnt(0)" ::: "memory");
            __builtin_amdgcn_s_barrier();
        }
    }

    // ---- fused epilogue ----
    // C/D 32x32: col = lane&31, row = 4*(lane>>5) + (reg&3) + 8*(reg>>2)
    // acc[ti][0]=p_lin, [1]=theta, [2]=inp_re, [3]=inp_im
    const int col = n0 + wc * 32 + L;
    const float bp = b_p[col], bt = b_th[col], br = b_r[col], bi = b_i[col];
    const int rowb = m0 + wr * 64 + 4 * hi;
#pragma unroll
    for (int ti = 0; ti < 2; ++ti) {
#pragma unroll
        for (int r = 0; r < 16; ++r) {
            const int row = rowb + ti * 32 + (r & 3) + 8 * (r >> 2);
            const float pl  = acc[ti][0][r] + bp;
            const float th  = acc[ti][1][r] + bt;
            const float ire = acc[ti][2][r] + br;
            const float iim = acc[ti][3][r] + bi;
            const float p = 1.f / (1.f + __expf(-pl));
            float s, ct;
            __sincosf(th, &s, &ct);
            const size_t base = (size_t)row * 4096 + col;
            const float hre = h_prev[base];
            const float him = h_prev[base + 2048];
            const float rre = ct * hre - s * him;
            const float rim = s * hre + ct * him;
            out[base]        = (1.f - p) * rre + p * ire;
            out[base + 2048] = (1.f - p) * rim + p * iim;
        }
    }
}

extern "C" void kernel_launch(void* const* d_in, const int* in_sizes, int n_in,
                              void* d_out, int out_size, void* d_ws, size_t ws_size,
                              hipStream_t stream) {
    (void)in_sizes; (void)n_in; (void)out_size; (void)ws_size;
    const float* e_t   = (const float*)d_in[0];
    const float* h_prv = (const float*)d_in[1];
    const float* W_p   = (const float*)d_in[2];
    const float* b_p   = (const float*)d_in[3];
    const float* W_th  = (const float*)d_in[4];
    const float* b_th  = (const float*)d_in[5];
    const float* W_r   = (const float*)d_in[6];
    const float* b_r   = (const float*)d_in[7];
    const float* W_i   = (const float*)d_in[8];
    const float* b_i   = (const float*)d_in[9];
    float* out = (float*)d_out;

    // workspace: W_cat bf16 [8192][2048] (32MB) then E bf16 [8192][2048] (32MB)
    unsigned short* Wbf = (unsigned short*)d_ws;
    unsigned short* Ebf = Wbf + (size_t)8192 * 2048;

    cvt_all<<<16384, 256, 0, stream>>>(W_p, W_th, W_r, W_i, e_t, Wbf, Ebf);

    // 32 m-tiles (256 rows, fast axis) x 32 d-tiles (64 dcols x 4 mats, slow)
    dim3 grid(32, 32);
    mipt_main<<<grid, 512, 0, stream>>>(Ebf, Wbf, b_p, b_th, b_r, b_i, h_prv, out);
}

// Round 3
// 583.186 us; speedup vs baseline: 1.2721x; 1.1190x over previous
//
#include <hip/hip_runtime.h>

// MIPTCell: proj = e @ [Wp;Wth;Wr;Wi]^T + b  (M=8192, N=4*2048, K=2048)
// bf16 32x32x16 MFMA GEMM fused with sigmoid/rot/gate epilogue.
//
// Schedule (round 3 — "minimum 2-phase" per K-tile, NO per-phase barriers):
//   block = 512 thr / 8 waves; tile 256 rows x 64 dcols x 4 mats (eff 256x256)
//   BK=64, double-buffered LDS (128 KB). Per K-tile:
//     STAGE(next tile, 8 gload_lds) ; 4 k-steps of {6 ds_read_b128 || 8 MFMA}
//     (compiler interleaves via counted lgkmcnt -> LDS port overlaps MFMA pipe)
//     ; one __syncthreads() (vmcnt(0)+lgkmcnt(0)+barrier) per tile.
//   Prefetch distance = full tile (~2000+ cyc) so the drain is free.
//   Grid: m-tiles fast, n-tiles slow (no XCD swizzle) — all XCDs share the
//   same narrow W band + synced E streams through L3 (fetch ~262 MB).
//   XOR-8 chunk swizzle: LDS(row, slot s) holds global chunk s ^ (row&7);
//   applied on the global source (gload_lds writes linearly) and on ds_read.
//   Wave (wr=w>>1, wc=w&1) owns rows wr*64+{0,32}, dcols wc*32+L, all 4 mats
//   -> acc[2][4] f32x16, epilogue register-local.

typedef float f32x16 __attribute__((ext_vector_type(16)));
typedef __bf16 bf16x8 __attribute__((ext_vector_type(8)));
typedef short short8 __attribute__((ext_vector_type(8)));

__device__ __forceinline__ unsigned short f2bf(float f) {
    unsigned u = __float_as_uint(f);
    u += 0x7fffu + ((u >> 16) & 1u);   // round-to-nearest-even
    return (unsigned short)(u >> 16);
}

// Fused fp32->bf16 convert for all 5 tensors in ONE launch.
__global__ __launch_bounds__(256) void cvt_all(
    const float* __restrict__ W_p, const float* __restrict__ W_th,
    const float* __restrict__ W_r, const float* __restrict__ W_i,
    const float* __restrict__ e_t,
    unsigned short* __restrict__ Wbf, unsigned short* __restrict__ Ebf) {
    const long i = (long)blockIdx.x * 256 + threadIdx.x;   // < 4194304
    const float* src;
    unsigned short* dst;
    size_t local;
    if (i < 2097152) {
        const int m = (int)(i >> 19);
        local = (size_t)(i & 524287) * 8;
        src = (m == 0) ? W_p : (m == 1) ? W_th : (m == 2) ? W_r : W_i;
        dst = Wbf + (size_t)m * 4194304 + local;
    } else {
        local = (size_t)(i - 2097152) * 8;
        src = e_t;
        dst = Ebf + local;
    }
    const float4* s4 = (const float4*)(src + local);
    float4 v0 = s4[0], v1 = s4[1];
    ushort4 o0, o1;
    o0.x = f2bf(v0.x); o0.y = f2bf(v0.y); o0.z = f2bf(v0.z); o0.w = f2bf(v0.w);
    o1.x = f2bf(v1.x); o1.y = f2bf(v1.y); o1.z = f2bf(v1.z); o1.w = f2bf(v1.w);
    ((ushort4*)dst)[0] = o0;
    ((ushort4*)dst)[1] = o1;
}

__device__ __forceinline__ void load16_lds(const unsigned short* g, unsigned short* l) {
    __builtin_amdgcn_global_load_lds((const __attribute__((address_space(1))) void*)g,
                                     (__attribute__((address_space(3))) void*)l,
                                     16, 0, 0);
}

__device__ __forceinline__ bf16x8 ldfrag(const unsigned short* p) {
    return __builtin_bit_cast(bf16x8, *(const short8*)p);
}

__global__ __launch_bounds__(512, 2) void mipt_main(
    const unsigned short* __restrict__ E,   // [8192][2048] bf16
    const unsigned short* __restrict__ W,   // [8192][2048] bf16 (Wp;Wth;Wr;Wi)
    const float* __restrict__ b_p, const float* __restrict__ b_th,
    const float* __restrict__ b_r, const float* __restrict__ b_i,
    const float* __restrict__ h_prev,       // [8192][4096] fp32
    float* __restrict__ out)                // [8192][4096] fp32
{
    __shared__ unsigned short As[2 * 256 * 64];   // 64 KB, 2 buffers
    __shared__ unsigned short Bs[2 * 256 * 64];   // 64 KB, 2 buffers

    const int tid  = threadIdx.x;
    const int w    = tid >> 6;     // 0..7
    const int lane = tid & 63;
    const int wr   = w >> 1;       // 0..3 : 64-row group
    const int wc   = w & 1;        // 0..1 : 32-dcol group

    // m-tiles fast (blockIdx.x), n-tiles slow (blockIdx.y)
    const int m0 = blockIdx.x * 256;
    const int n0 = blockIdx.y * 64;

    f32x16 acc[2][4];
#pragma unroll
    for (int i = 0; i < 2; ++i)
#pragma unroll
        for (int j = 0; j < 4; ++j)
#pragma unroll
            for (int r = 0; r < 16; ++r) acc[i][j][r] = 0.f;

    // ---- staging addressing ----
    // Wave w stages A rows [w*32,w*32+32) and Bs rows [w*32,w*32+32).
    // Per gload: 8 rows (128B each), lane -> row sr=lane>>3, slot lane&7.
    // Pre-swizzled global source: chunk_g = (lane&7) ^ sr  (both-sides XOR-8).
    const int sr = lane >> 3;
    const int sc = ((lane & 7) ^ sr) * 8;
    const unsigned short* Ag = E + (size_t)(m0 + w * 32 + sr) * 2048 + sc;
    // Bs row rb = mat*64 + dd : wave w -> mat = w>>1, dd = (w&1)*32 + j*8 + sr
    const unsigned short* Bg = W + (size_t)(wr * 2048 + n0 + wc * 32 + sr) * 2048 + sc;
    const int dA = w * 2048;   // element offset of wave's 32-row LDS panel

    // ---- fragment addressing (32x32x16: A[m=lane&31][k=(lane>>5)*8+j]) ----
    const int L  = lane & 31;
    const int hi = lane >> 5;
    const int r7 = L & 7;
    const int aoff = (wr * 64 + L) * 64;   // A row = wr*64 + ti*32 + L
    const int boff = (wc * 32 + L) * 64;   // B row = tj*64 + wc*32 + L

    // ---- prologue: stage K-tile 0 into buffer 0 ----
#pragma unroll
    for (int j = 0; j < 4; ++j) {
        load16_lds(Ag + (size_t)(j * 8) * 2048, As + dA + j * 512);
        load16_lds(Bg + (size_t)(j * 8) * 2048, Bs + dA + j * 512);
    }
    __syncthreads();

#pragma unroll 1
    for (int t = 0; t < 32; ++t) {
        const int so = (t & 1) << 14;      // current buffer offset (elems)
        const int sn = so ^ 16384;         // next buffer offset

        // issue the ENTIRE next K-tile up front: prefetch distance = 1 tile
        if (t < 31) {
            const unsigned short* Agt = Ag + (size_t)(t + 1) * 64;
            const unsigned short* Bgt = Bg + (size_t)(t + 1) * 64;
#pragma unroll
            for (int j = 0; j < 4; ++j) {
                load16_lds(Agt + (size_t)(j * 8) * 2048, As + sn + dA + j * 512);
                load16_lds(Bgt + (size_t)(j * 8) * 2048, Bs + sn + dA + j * 512);
            }
        }

        const unsigned short* aC = As + so + aoff;
        const unsigned short* bC = Bs + so + boff;

        // 4 k-steps, NO barriers between: ds_reads of step q+1 overlap MFMA
        // of step q (compiler's counted lgkmcnt scheduling).
#pragma unroll
        for (int q = 0; q < 4; ++q) {
            const int qo = ((2 * q + hi) ^ r7) * 8;   // chunk = 2q + hi
            bf16x8 a0 = ldfrag(aC + qo);
            bf16x8 a1 = ldfrag(aC + 2048 + qo);
            bf16x8 b0 = ldfrag(bC + qo);
            bf16x8 b1 = ldfrag(bC + 4096 + qo);
            bf16x8 b2 = ldfrag(bC + 8192 + qo);
            bf16x8 b3 = ldfrag(bC + 12288 + qo);
            __builtin_amdgcn_s_setprio(1);
            acc[0][0] = __builtin_amdgcn_mfma_f32_32x32x16_bf16(a0, b0, acc[0][0], 0, 0, 0);
            acc[1][0] = __builtin_amdgcn_mfma_f32_32x32x16_bf16(a1, b0, acc[1][0], 0, 0, 0);
            acc[0][1] = __builtin_amdgcn_mfma_f32_32x32x16_bf16(a0, b1, acc[0][1], 0, 0, 0);
            acc[1][1] = __builtin_amdgcn_mfma_f32_32x32x16_bf16(a1, b1, acc[1][1], 0, 0, 0);
            acc[0][2] = __builtin_amdgcn_mfma_f32_32x32x16_bf16(a0, b2, acc[0][2], 0, 0, 0);
            acc[1][2] = __builtin_amdgcn_mfma_f32_32x32x16_bf16(a1, b2, acc[1][2], 0, 0, 0);
            acc[0][3] = __builtin_amdgcn_mfma_f32_32x32x16_bf16(a0, b3, acc[0][3], 0, 0, 0);
            acc[1][3] = __builtin_amdgcn_mfma_f32_32x32x16_bf16(a1, b3, acc[1][3], 0, 0, 0);
            __builtin_amdgcn_s_setprio(0);
        }

        // one drain + barrier per tile (vmcnt(0) lgkmcnt(0) + s_barrier):
        // staged loads were issued ~a full tile ago -> drain is ~free.
        __syncthreads();
    }

    // ---- fused epilogue ----
    // C/D 32x32: col = lane&31, row = 4*(lane>>5) + (reg&3) + 8*(reg>>2)
    // acc[ti][0]=p_lin, [1]=theta, [2]=inp_re, [3]=inp_im
    const int col = n0 + wc * 32 + L;
    const float bp = b_p[col], bt = b_th[col], br = b_r[col], bi = b_i[col];
    const int rowb = m0 + wr * 64 + 4 * hi;
#pragma unroll
    for (int ti = 0; ti < 2; ++ti) {
#pragma unroll
        for (int r = 0; r < 16; ++r) {
            const int row = rowb + ti * 32 + (r & 3) + 8 * (r >> 2);
            const float pl  = acc[ti][0][r] + bp;
            const float th  = acc[ti][1][r] + bt;
            const float ire = acc[ti][2][r] + br;
            const float iim = acc[ti][3][r] + bi;
            const float p = 1.f / (1.f + __expf(-pl));
            float s, ct;
            __sincosf(th, &s, &ct);
            const size_t base = (size_t)row * 4096 + col;
            const float hre = h_prev[base];
            const float him = h_prev[base + 2048];
            const float rre = ct * hre - s * him;
            const float rim = s * hre + ct * him;
            out[base]        = (1.f - p) * rre + p * ire;
            out[base + 2048] = (1.f - p) * rim + p * iim;
        }
    }
}

extern "C" void kernel_launch(void* const* d_in, const int* in_sizes, int n_in,
                              void* d_out, int out_size, void* d_ws, size_t ws_size,
                              hipStream_t stream) {
    (void)in_sizes; (void)n_in; (void)out_size; (void)ws_size;
    const float* e_t   = (const float*)d_in[0];
    const float* h_prv = (const float*)d_in[1];
    const float* W_p   = (const float*)d_in[2];
    const float* b_p   = (const float*)d_in[3];
    const float* W_th  = (const float*)d_in[4];
    const float* b_th  = (const float*)d_in[5];
    const float* W_r   = (const float*)d_in[6];
    const float* b_r   = (const float*)d_in[7];
    const float* W_i   = (const float*)d_in[8];
    const float* b_i   = (const float*)d_in[9];
    float* out = (float*)d_out;

    // workspace: W_cat bf16 [8192][2048] (32MB) then E bf16 [8192][2048] (32MB)
    unsigned short* Wbf = (unsigned short*)d_ws;
    unsigned short* Ebf = Wbf + (size_t)8192 * 2048;

    cvt_all<<<16384, 256, 0, stream>>>(W_p, W_th, W_r, W_i, e_t, Wbf, Ebf);

    // 32 m-tiles (256 rows, fast axis) x 32 d-tiles (64 dcols x 4 mats, slow)
    dim3 grid(32, 32);
    mipt_main<<<grid, 512, 0, stream>>>(Ebf, Wbf, b_p, b_th, b_r, b_i, h_prv, out);
}